// Round 6
// baseline (247.723 us; speedup 1.0000x reference)
//
#include <hip/hip_runtime.h>
#include <hip/hip_bf16.h>
#include <math.h>

#define MEM 2048
#define NF4 512   // float4 per 2048-row

__device__ __forceinline__ float dot4(float4 a, float4 b) {
    return a.x * b.x + a.y * b.y + a.z * b.z + a.w * b.w;
}

__device__ __forceinline__ float wave_reduce(float v) {
#pragma unroll
    for (int off = 32; off > 0; off >>= 1)
        v += __shfl_down(v, off, 64);
    return v;
}

__device__ __forceinline__ float sigmoidf_(float x) {
    return 1.0f / (1.0f + expf(-x));
}

// ws layout (floats):
//  slot0 [0*2048): dwl (k1)  -> overwritten by la (k_mid)
//  slot1 [1*2048): dwr (k1)  -> overwritten by ra (k_mid)
//  slot2 [2*2048): dus (k1)  -> overwritten by part[m=0] (k2)
//  slot3 [3*2048): pl  (k1)  -> overwritten by part[m=1] (k2)
//  slot4 [4*2048): pr  (k1)  -> overwritten by part[m=2] (k2)
//  slot5..9      : part[m=3..7] (k2)

// k1: 1536 blocks x 128 threads, NO LDS, NO barriers. bx>>9 = matrix m
// (0=Wh,1=Us,2=ma), bx&511 = half-slab (4 rows). Wave = 2 rows x 8 chunks.
// x-vectors (lh/rh/S, 8KB each) are read per-lane from global — L1-resident
// after first touch. 16 WG/CU x 2 waves = full 32-wave occupancy.
__global__ __launch_bounds__(128) void
k1_slab(const float* __restrict__ lh, const float* __restrict__ rh,
        const float* __restrict__ S,
        const float* __restrict__ Wh_w, const float* __restrict__ Us_w,
        const float* __restrict__ ma_w,
        float* __restrict__ ws)
{
    const int t  = threadIdx.x;
    const int bx = blockIdx.x;
    const int m  = bx >> 9;
    const int hs = bx & 511;
    const int wv = t >> 6, ln = t & 63;
    const int row0 = hs * 4 + wv * 2;

    const float* W  = (m == 0) ? Wh_w : (m == 1) ? Us_w : ma_w;
    const float* x1 = (m == 1) ? S : lh;
    const float* x2 = (m == 1) ? S : rh;

    const float4* __restrict__ w0 = (const float4*)(W + (size_t)row0 * MEM);
    const float4* __restrict__ w1 = w0 + NF4;
    const float4* __restrict__ x14 = (const float4*)x1;
    const float4* __restrict__ x24 = (const float4*)x2;

    float a00 = 0.f, a01 = 0.f, a10 = 0.f, a11 = 0.f;
#pragma unroll
    for (int j = 0; j < 8; ++j) {
        const int idx = j * 64 + ln;
        const float4 A = w0[idx];
        const float4 B = w1[idx];
        const float4 p = x14[idx];
        const float4 q = x24[idx];
        a00 += dot4(A, p); a01 += dot4(A, q);
        a10 += dot4(B, p); a11 += dot4(B, q);
    }
    a00 = wave_reduce(a00); a01 = wave_reduce(a01);
    a10 = wave_reduce(a10); a11 = wave_reduce(a11);

    if (ln == 0) {
        if (m == 0) {            // Wh: dwl = W·lh, dwr = W·rh
            ws[row0] = a00; ws[row0 + 1] = a10;
            ws[MEM + row0] = a01; ws[MEM + row0 + 1] = a11;
        } else if (m == 1) {     // Us: dus = W·S
            ws[2 * MEM + row0] = a00; ws[2 * MEM + row0 + 1] = a10;
        } else {                 // ma: pl = W·lh, pr = W·rh
            ws[3 * MEM + row0] = a00; ws[3 * MEM + row0 + 1] = a10;
            ws[4 * MEM + row0] = a01; ws[4 * MEM + row0 + 1] = a11;
        }
    }
}

// k_mid: ONE block. alpha from raw dots, then la/ra into ws slots 0/1.
__global__ __launch_bounds__(1024) void
k_mid(const float* __restrict__ w, const float* __restrict__ Wh_b,
      const float* __restrict__ Us_b, const float* __restrict__ ma_b,
      float* __restrict__ ws)
{
    __shared__ float s_red[16][2];
    __shared__ float s_al[2];

    const int t = threadIdx.x;
    float el = 0.f, er = 0.f;
    for (int j = t; j < MEM; j += 1024) {
        const float us = ws[2 * MEM + j] + Us_b[j];
        const float bb = Wh_b[j] + us;
        const float ml = tanhf(ws[j] + bb);
        const float mr = tanhf(ws[MEM + j] + bb);
        const float wj = w[j];
        el += wj * ml; er += wj * mr;
    }
    el = wave_reduce(el);
    er = wave_reduce(er);
    const int wv = t >> 6, ln = t & 63;
    if (ln == 0) { s_red[wv][0] = el; s_red[wv][1] = er; }
    __syncthreads();
    if (t == 0) {
        float e0 = 0.f, e1 = 0.f;
#pragma unroll
        for (int k = 0; k < 16; ++k) { e0 += s_red[k][0]; e1 += s_red[k][1]; }
        const float d = e0 + e1;
        s_al[0] = e0 / d;
        s_al[1] = e1 / d;
    }
    __syncthreads();
    const float al = s_al[0];
    const float ar = s_al[1];
    for (int j = t; j < MEM; j += 1024) {
        const float mb = ma_b[j];
        const float la = tanhf(al * ws[3 * MEM + j] + mb);
        const float ra = tanhf(ar * ws[4 * MEM + j] + mb);
        ws[j] = la;          // safe: this thread's dwl[j]/dwr[j] consumed pre-barrier
        ws[MEM + j] = ra;
    }
}

// k2: 4096 blocks x 128 threads, NO LDS, NO barriers. bx>>9 = gate matrix m
// (even→la, odd→ra), bx&511 = half-slab (4 rows). Wave = 2 rows x 8 chunks.
// x (la/ra, 8KB each) read per-lane from global — L1-resident.
__global__ __launch_bounds__(128) void
k2_slab(const float* __restrict__ ilh_w,  const float* __restrict__ irh_w,
        const float* __restrict__ lflh_w, const float* __restrict__ lfrh_w,
        const float* __restrict__ rflh_w, const float* __restrict__ rfrh_w,
        const float* __restrict__ ulh_w,  const float* __restrict__ urh_w,
        float* __restrict__ ws)
{
    const int t  = threadIdx.x;
    const int bx = blockIdx.x;
    const int m  = bx >> 9;
    const int hs = bx & 511;
    const int wv = t >> 6, ln = t & 63;
    const int row0 = hs * 4 + wv * 2;

    const float* Wt[8] = {ilh_w, irh_w, lflh_w, lfrh_w, rflh_w, rfrh_w, ulh_w, urh_w};
    const float* W = Wt[m];
    const float* x = ws + (size_t)(m & 1) * MEM;   // even=la, odd=ra

    const float4* __restrict__ w0 = (const float4*)(W + (size_t)row0 * MEM);
    const float4* __restrict__ w1 = w0 + NF4;
    const float4* __restrict__ x4 = (const float4*)x;

    float a0 = 0.f, a1 = 0.f;
#pragma unroll
    for (int j = 0; j < 8; ++j) {
        const int idx = j * 64 + ln;
        const float4 A  = w0[idx];
        const float4 B  = w1[idx];
        const float4 xv = x4[idx];
        a0 += dot4(A, xv);
        a1 += dot4(B, xv);
    }
    a0 = wave_reduce(a0);
    a1 = wave_reduce(a1);
    if (ln == 0) {
        float* p = ws + (size_t)(2 + m) * MEM;
        p[row0]     = a0;
        p[row0 + 1] = a1;
    }
}

// k3: combine partials -> gates -> c, h. grid 8x256.
__global__ __launch_bounds__(256) void
k3_combine(const float* __restrict__ lc, const float* __restrict__ rc,
           const float* __restrict__ ilh_b,  const float* __restrict__ irh_b,
           const float* __restrict__ lflh_b, const float* __restrict__ lfrh_b,
           const float* __restrict__ rflh_b, const float* __restrict__ rfrh_b,
           const float* __restrict__ ulh_b,  const float* __restrict__ urh_b,
           const float* __restrict__ ws, float* __restrict__ out)
{
    const int j = blockIdx.x * 256 + threadIdx.x;
    const float* P = ws + 2 * MEM;
    const float gi = sigmoidf_(P[j]           + P[MEM + j]     + ilh_b[j]  + irh_b[j]);
    const float lf = sigmoidf_(P[2 * MEM + j] + P[3 * MEM + j] + lflh_b[j] + lfrh_b[j]);
    const float rf = sigmoidf_(P[4 * MEM + j] + P[5 * MEM + j] + rflh_b[j] + rfrh_b[j]);
    const float u  = tanhf(    P[6 * MEM + j] + P[7 * MEM + j] + ulh_b[j]  + urh_b[j]);
    const float c  = gi * u + lf * lc[j] + rf * rc[j];
    out[j]       = c;
    out[MEM + j] = tanhf(c);
}

extern "C" void kernel_launch(void* const* d_in, const int* in_sizes, int n_in,
                              void* d_out, int out_size, void* d_ws, size_t ws_size,
                              hipStream_t stream) {
    const float* lc = (const float*)d_in[0];
    const float* lh = (const float*)d_in[1];
    const float* rc = (const float*)d_in[2];
    const float* rh = (const float*)d_in[3];
    const float* S  = (const float*)d_in[4];
    const float* w  = (const float*)d_in[5];
    const float* Wh_w   = (const float*)d_in[6];   const float* Wh_b   = (const float*)d_in[7];
    const float* Us_w   = (const float*)d_in[8];   const float* Us_b   = (const float*)d_in[9];
    const float* ma_w   = (const float*)d_in[10];  const float* ma_b   = (const float*)d_in[11];
    const float* ilh_w  = (const float*)d_in[12];  const float* ilh_b  = (const float*)d_in[13];
    const float* irh_w  = (const float*)d_in[14];  const float* irh_b  = (const float*)d_in[15];
    const float* lflh_w = (const float*)d_in[16];  const float* lflh_b = (const float*)d_in[17];
    const float* lfrh_w = (const float*)d_in[18];  const float* lfrh_b = (const float*)d_in[19];
    const float* rflh_w = (const float*)d_in[20];  const float* rflh_b = (const float*)d_in[21];
    const float* rfrh_w = (const float*)d_in[22];  const float* rfrh_b = (const float*)d_in[23];
    const float* ulh_w  = (const float*)d_in[24];  const float* ulh_b  = (const float*)d_in[25];
    const float* urh_w  = (const float*)d_in[26];  const float* urh_b  = (const float*)d_in[27];

    float* out = (float*)d_out;
    float* ws  = (float*)d_ws;

    k1_slab<<<1536, 128, 0, stream>>>(lh, rh, S, Wh_w, Us_w, ma_w, ws);

    k_mid<<<1, 1024, 0, stream>>>(w, Wh_b, Us_b, ma_b, ws);

    k2_slab<<<4096, 128, 0, stream>>>(ilh_w, irh_w, lflh_w, lfrh_w,
                                      rflh_w, rfrh_w, ulh_w, urh_w, ws);

    k3_combine<<<8, 256, 0, stream>>>(lc, rc, ilh_b, irh_b, lflh_b, lfrh_b,
                                      rflh_b, rfrh_b, ulh_b, urh_b, ws, out);
}